// Round 1
// baseline (413.394 us; speedup 1.0000x reference)
//
#include <hip/hip_runtime.h>
#include <math.h>

// GAT layer: N=50000 nodes, E=800000 edges, DIN=128, EDIM=64, DOUT=128
// ws layout (floats): asrc[N] | adst[N] | e[E] | emax[N] | denom[N] | z[N*64]

#define DIN 128
#define EDIM 64
#define DOUT 128
#define KDIM 192   // DIN + EDIM

// ---------------- K1: per-node attention scalars ----------------
// one wave per node: a_src[n] = dot(nfeats[n], attn_w[0:128]),
//                    a_dst[n] = dot(nfeats[n], attn_w[128:256])
__global__ void k1_node_attn(const float* __restrict__ nf,
                             const float* __restrict__ aw,
                             float* __restrict__ asrc,
                             float* __restrict__ adst, int n) {
    int gid  = blockIdx.x * blockDim.x + threadIdx.x;
    int wid  = gid >> 6;
    int lane = threadIdx.x & 63;
    if (wid >= n) return;
    float2 x  = reinterpret_cast<const float2*>(nf)[(size_t)wid * 64 + lane];
    float2 w1 = reinterpret_cast<const float2*>(aw)[lane];
    float2 w2 = reinterpret_cast<const float2*>(aw)[64 + lane];
    float s1 = x.x * w1.x + x.y * w1.y;
    float s2 = x.x * w2.x + x.y * w2.y;
#pragma unroll
    for (int m = 32; m; m >>= 1) {
        s1 += __shfl_xor(s1, m, 64);
        s2 += __shfl_xor(s2, m, 64);
    }
    if (lane == 0) { asrc[wid] = s1; adst[wid] = s2; }
}

// ---------------- K2: per-edge logit + segment max ----------------
// e >= 0 after relu, so atomicMax on float bits (as uint) with emax init 0
// exactly reproduces segment_max followed by isneginf->0.
__global__ void k2_edge_logit(const float* __restrict__ asrc,
                              const float* __restrict__ adst,
                              const int* __restrict__ src,
                              const int* __restrict__ dst,
                              const float* __restrict__ ab,
                              float* __restrict__ e,
                              float* __restrict__ emax, int ne) {
    int i = blockIdx.x * blockDim.x + threadIdx.x;
    if (i >= ne) return;
    int d = dst[i];
    float ev = fmaxf(asrc[src[i]] + adst[d] + ab[0], 0.0f);
    e[i] = ev;
    atomicMax(reinterpret_cast<unsigned int*>(emax) + d, __float_as_uint(ev));
}

// ---------------- K3: per-edge exp + scatter-accumulate ----------------
// one wave (64 lanes) per edge: lane c handles efeats channel c.
// denom[d] += ex ; z[d][c] += ex * efeats[edge][c]  (unnormalized)
__global__ void k3_scatter(const float* __restrict__ e,
                           const float* __restrict__ emax,
                           const int* __restrict__ dst,
                           const float* __restrict__ ef,
                           float* __restrict__ denom,
                           float* __restrict__ z, int ne) {
    int gid  = blockIdx.x * blockDim.x + threadIdx.x;
    int edge = gid >> 6;
    int lane = threadIdx.x & 63;
    if (edge >= ne) return;
    int d = dst[edge];
    float ex = expf(e[edge] - emax[d]);
    if (lane == 0) atomicAdd(denom + d, ex);
    float v = ex * ef[(size_t)edge * EDIM + lane];
    atomicAdd(z + (size_t)d * EDIM + lane, v);
}

// ---------------- K4: fused normalize + apply GEMM + relu ----------------
// out[n] = relu(W @ [nfeats[n]; z[n]/denom[n]] + b)
// W (128x192) transposed into LDS with stride-132 pad (8-way max on the
// one-time staging write, conflict-free float4 compute reads).
// 64-node x tile in LDS, stride-193 pad (ng-strided reads hit distinct banks).
// Each thread: 4 nodes x 8 outputs = 32 accumulators -> 1.5 LDS bytes/FMA.
#define WT_STRIDE 132
#define XS_STRIDE 193
#define TILE_NODES 64

__global__ __launch_bounds__(256, 1) void k4_apply(
        const float* __restrict__ nf, const float* __restrict__ z,
        const float* __restrict__ denom, const float* __restrict__ W,
        const float* __restrict__ bias, float* __restrict__ out, int n) {
    __shared__ float Wt[KDIM * WT_STRIDE];
    __shared__ float xs[TILE_NODES * XS_STRIDE];
    int tid = threadIdx.x;

    // stage W transposed: Wt[k][o] = W[o][k]
    for (int idx = tid; idx < DOUT * KDIM; idx += 256) {
        int o = idx / KDIM;
        int k = idx - o * KDIM;
        Wt[k * WT_STRIDE + o] = W[idx];
    }

    int og = tid & 15;   // output group: outputs og*8 .. og*8+7
    int ng = tid >> 4;   // node group:   nodes  ng*4 .. ng*4+3 within tile

    float4 b0 = *reinterpret_cast<const float4*>(bias + og * 8);
    float4 b1 = *reinterpret_cast<const float4*>(bias + og * 8 + 4);

    int ntiles = (n + TILE_NODES - 1) / TILE_NODES;
    for (int t = blockIdx.x; t < ntiles; t += gridDim.x) {
        int n0 = t * TILE_NODES;
        __syncthreads();  // protect xs (and cover W staging on first iter)

        // stage x = [nfeats ; z/denom] for 64 nodes
        for (int idx = tid; idx < TILE_NODES * KDIM; idx += 256) {
            int ln = idx / KDIM;
            int k  = idx - ln * KDIM;
            int node = n0 + ln;
            float v = 0.0f;
            if (node < n) {
                if (k < DIN) {
                    v = nf[(size_t)node * DIN + k];
                } else {
                    float dn = denom[node];
                    v = z[(size_t)node * EDIM + (k - DIN)] / (dn > 0.0f ? dn : 1.0f);
                }
            }
            xs[ln * XS_STRIDE + k] = v;
        }
        __syncthreads();

        float acc[4][8];
#pragma unroll
        for (int i = 0; i < 4; ++i)
#pragma unroll
            for (int j = 0; j < 8; ++j) acc[i][j] = 0.0f;

        const float* xp = xs + (ng * 4) * XS_STRIDE;
#pragma unroll 2
        for (int k = 0; k < KDIM; ++k) {
            const float* wr = &Wt[k * WT_STRIDE + og * 8];
            float4 w0 = *reinterpret_cast<const float4*>(wr);
            float4 w1 = *reinterpret_cast<const float4*>(wr + 4);
            float wv[8] = {w0.x, w0.y, w0.z, w0.w, w1.x, w1.y, w1.z, w1.w};
#pragma unroll
            for (int i = 0; i < 4; ++i) {
                float xv = xp[i * XS_STRIDE + k];
#pragma unroll
                for (int j = 0; j < 8; ++j)
                    acc[i][j] = fmaf(xv, wv[j], acc[i][j]);
            }
        }

#pragma unroll
        for (int i = 0; i < 4; ++i) {
            int node = n0 + ng * 4 + i;
            if (node < n) {
                float4 r0, r1;
                r0.x = fmaxf(acc[i][0] + b0.x, 0.0f);
                r0.y = fmaxf(acc[i][1] + b0.y, 0.0f);
                r0.z = fmaxf(acc[i][2] + b0.z, 0.0f);
                r0.w = fmaxf(acc[i][3] + b0.w, 0.0f);
                r1.x = fmaxf(acc[i][4] + b1.x, 0.0f);
                r1.y = fmaxf(acc[i][5] + b1.y, 0.0f);
                r1.z = fmaxf(acc[i][6] + b1.z, 0.0f);
                r1.w = fmaxf(acc[i][7] + b1.w, 0.0f);
                float* op = out + (size_t)node * DOUT + og * 8;
                *reinterpret_cast<float4*>(op)     = r0;
                *reinterpret_cast<float4*>(op + 4) = r1;
            }
        }
    }
}

extern "C" void kernel_launch(void* const* d_in, const int* in_sizes, int n_in,
                              void* d_out, int out_size, void* d_ws, size_t ws_size,
                              hipStream_t stream) {
    const float* nf   = (const float*)d_in[0];
    const float* ef   = (const float*)d_in[1];
    const int*   src  = (const int*)d_in[2];
    const int*   dst  = (const int*)d_in[3];
    const float* W    = (const float*)d_in[4];
    const float* bias = (const float*)d_in[5];
    const float* aw   = (const float*)d_in[6];
    const float* ab   = (const float*)d_in[7];
    float* out = (float*)d_out;

    int n  = in_sizes[0] / DIN;   // 50000
    int ne = in_sizes[2];         // 800000

    float* ws    = (float*)d_ws;
    float* asrc  = ws;
    float* adst  = asrc + n;
    float* e     = adst + n;
    float* emax  = e + ne;
    float* denom = emax + n;
    float* z     = denom + n;

    // zero emax, denom, z (must be re-zeroed every call)
    hipMemsetAsync(emax, 0, (size_t)(2 * n + (size_t)n * EDIM) * sizeof(float), stream);

    k1_node_attn<<<(n * 64 + 255) / 256, 256, 0, stream>>>(nf, aw, asrc, adst, n);
    k2_edge_logit<<<(ne + 255) / 256, 256, 0, stream>>>(asrc, adst, src, dst, ab, e, emax, ne);
    k3_scatter<<<(int)(((size_t)ne * 64 + 255) / 256), 256, 0, stream>>>(e, emax, dst, ef, denom, z, ne);
    k4_apply<<<256, 256, 0, stream>>>(nf, z, denom, W, bias, out, n);
}